// Round 4
// baseline (81.497 us; speedup 1.0000x reference)
//
#include <hip/hip_runtime.h>
#include <stdint.h>

// Problem dims (fixed by the reference's setup_inputs)
#define B    8
#define C    80
#define M    100
#define NPIX 16384          // 128*128
#define NT   128            // cells per block
#define NW   4              // waves per block (256 threads)

#define ALPHA_F 0.25f
#define EPS_F   1e-8f

// Order-preserving float -> uint32 map (total order; no NaNs expected here).
__device__ __forceinline__ uint32_t fkey(float f) {
    uint32_t u = __float_as_uint(f);
    return (u & 0x80000000u) ? ~u : (u | 0x80000000u);
}

// ---------------------------------------------------------------------------
// init: one wave per (b,m). cid = first argmax of one-hot row; keys = +inf.
// ---------------------------------------------------------------------------
__global__ __launch_bounds__(256) void init_kernel(
    const float* __restrict__ cls_true,   // (B*M, C)
    int* __restrict__ cids,
    unsigned long long* __restrict__ keys)
{
    const int bm   = blockIdx.x * NW + (threadIdx.x >> 6);
    const int lane = threadIdx.x & 63;
    if (bm >= B * M) return;

    const float* ct = cls_true + (size_t)bm * C;
    // key = (fkey(v) << 32) | (C-1-c): max over keys -> max v, tie -> min c
    const float v0 = ct[lane];
    unsigned long long k =
        ((unsigned long long)fkey(v0) << 32) | (unsigned int)(C - 1 - lane);
    if (lane + 64 < C) {
        const float v1 = ct[lane + 64];
        unsigned long long k1 =
            ((unsigned long long)fkey(v1) << 32) | (unsigned int)(C - 1 - (lane + 64));
        if (k1 > k) k = k1;
    }
    #pragma unroll
    for (int off = 32; off > 0; off >>= 1) {
        unsigned long long o = __shfl_xor(k, off, 64);
        if (o > k) k = o;
    }
    if (lane == 0) {
        cids[bm] = C - 1 - (int)(k & 0xFFFFFFFFull);
        keys[bm] = 0xFFFFFFFFFFFFFFFFull;
    }
}

// ---------------------------------------------------------------------------
// fused match: block = (tile of NT cells, b). Stage focal costs D (swizzled)
// in LDS; each wave privately owns m = w::NW, scans all NT cells, one packed
// shuffle-reduce + one atomicMin per m. No barriers in the m-loop.
// ---------------------------------------------------------------------------
__global__ __launch_bounds__(256, 4) void match_kernel(
    const float* __restrict__ cls_pred,   // (B, NPIX, C)
    const float* __restrict__ loc_pred,   // (B, NPIX, 4)
    const float* __restrict__ loc_true,   // (B, M, 4)
    const int*   __restrict__ cids,       // (B*M)
    unsigned long long* __restrict__ keys)// (B*M)
{
#pragma clang fp contract(off)
    // D[c][n] stored at c*NT + (n ^ (c & 31)) -- conflict-free write & read
    __shared__ float D[C * NT];           // 40,960 B -> 4 blocks/CU

    const int b    = blockIdx.y;
    const int n0   = blockIdx.x * NT;
    const int tid  = threadIdx.x;
    const int lane = tid & 63;
    const int w    = tid >> 6;

    // ---- stage focal class-cost tile (coalesced read, swizzled LDS write) ----
    const float* src = cls_pred + ((size_t)b * NPIX + n0) * C;
    #pragma unroll
    for (int k = 0; k < NT * C / 256; ++k) {   // 40 iters
        const int idx = k * 256 + tid;
        const int n = idx / C;
        const int c = idx - n * C;
        const float p = src[idx];
        const float q = 1.0f - p;
        const float pos = (ALPHA_F * (q * q)) * (-logf(p + EPS_F));
        const float neg = ((1.0f - ALPHA_F) * (p * p)) * (-logf(q + EPS_F));
        D[c * NT + (n ^ (c & 31))] = pos - neg;
    }

    // ---- per-lane boxes for cells lane, lane+64 (shared by all waves) ----
    const float inv = 1.0f / 128.0f;
    float py1[2], px1[2], py2[2], px2[2], pa[2];
    #pragma unroll
    for (int kk = 0; kk < 2; ++kk) {
        const int cell = kk * 64 + lane;
        const float4 lp = *(const float4*)(loc_pred + ((size_t)b * NPIX + n0 + cell) * 4);
        py1[kk] = lp.x * inv;
        px1[kk] = lp.y * inv;
        py2[kk] = lp.z * inv;
        px2[kk] = lp.w * inv;
        pa[kk]  = fmaxf(py2[kk] - py1[kk], 0.0f) * fmaxf(px2[kk] - px1[kk], 0.0f);
    }

    __syncthreads();

    // ---- m-loop: wave w owns m = w, w+4, ..., independent of other waves ----
    for (int m = w; m < M; m += NW) {
        const int bm  = b * M + m;
        const int cid = cids[bm];                 // wave-uniform scalar load
        const float ty1 = loc_true[bm * 4 + 0];
        const float tx1 = loc_true[bm * 4 + 1];
        const float ty2 = loc_true[bm * 4 + 2];
        const float tx2 = loc_true[bm * 4 + 3];
        const float t_area = fmaxf(ty2 - ty1, 0.0f) * fmaxf(tx2 - tx1, 0.0f);

        const int drow = cid * NT;
        const int sw   = cid & 31;

        float bestv = __builtin_huge_valf();
        int   bestn = 0;

        #pragma unroll
        for (int kk = 0; kk < 2; ++kk) {
            const int cell = kk * 64 + lane;
            const float d = D[drow + (cell ^ sw)];

            // reg: sum(|loc_true - loc_p|), left-assoc like np
            const float r = ((fabsf(ty1 - py1[kk]) + fabsf(tx1 - px1[kk]))
                             + fabsf(ty2 - py2[kk])) + fabsf(tx2 - px2[kk]);

            // giou
            const float ih = fmaxf(fminf(py2[kk], ty2) - fmaxf(py1[kk], ty1), 0.0f);
            const float iw = fmaxf(fminf(px2[kk], tx2) - fmaxf(px1[kk], tx1), 0.0f);
            const float inter = ih * iw;
            const float uni   = (pa[kk] + t_area) - inter;
            const float iou   = (uni > 0.0f) ? (inter / fmaxf(uni, EPS_F)) : 0.0f;
            const float eh = fmaxf(py2[kk], ty2) - fminf(py1[kk], ty1);
            const float ew = fmaxf(px2[kk], tx2) - fminf(px1[kk], tx1);
            const float enc = eh * ew;
            const float pen = (enc > 0.0f) ? ((enc - uni) / fmaxf(enc, EPS_F)) : 0.0f;
            const float gl  = 1.0f - (iou - pen);

            const float total = ((2.0f * d) + (5.0f * r)) + (2.0f * gl);

            if (total < bestv) { bestv = total; bestn = n0 + cell; }  // strict < => first index
        }

        unsigned long long key =
            ((unsigned long long)fkey(bestv) << 32) | (unsigned int)bestn;

        #pragma unroll
        for (int off = 32; off > 0; off >>= 1) {
            unsigned long long o = __shfl_xor(key, off, 64);
            if (o < key) key = o;
        }
        if (lane == 0)
            atomicMin(&keys[bm], key);
    }
}

// ---------------------------------------------------------------------------
// writeout: unpack to (b, argmin, cid) int32
// ---------------------------------------------------------------------------
__global__ void write_out_kernel(const unsigned long long* __restrict__ keys,
                                 const int* __restrict__ cids,
                                 int* __restrict__ out) {
    int i = blockIdx.x * blockDim.x + threadIdx.x;
    if (i >= B * M) return;
    out[i * 3 + 0] = i / M;
    out[i * 3 + 1] = (int)(keys[i] & 0xFFFFFFFFull);
    out[i * 3 + 2] = cids[i];
}

// ===========================================================================
extern "C" void kernel_launch(void* const* d_in, const int* in_sizes, int n_in,
                              void* d_out, int out_size, void* d_ws, size_t ws_size,
                              hipStream_t stream) {
    const float* cls_pred = (const float*)d_in[0];
    const float* loc_pred = (const float*)d_in[1];
    const float* cls_true = (const float*)d_in[2];
    const float* loc_true = (const float*)d_in[3];
    int* out = (int*)d_out;

    unsigned long long* keys = (unsigned long long*)d_ws;
    int* cids = (int*)((char*)d_ws + (size_t)B * M * sizeof(unsigned long long));

    init_kernel<<<(B * M + NW - 1) / NW, 256, 0, stream>>>(cls_true, cids, keys);
    match_kernel<<<dim3(NPIX / NT, B), 256, 0, stream>>>(
        cls_pred, loc_pred, loc_true, cids, keys);
    write_out_kernel<<<(B * M + 255) / 256, 256, 0, stream>>>(keys, cids, out);
}

// Round 5
// 66.019 us; speedup vs baseline: 1.2345x; 1.2345x over previous
//
#include <hip/hip_runtime.h>
#include <stdint.h>

// Problem dims (fixed by the reference's setup_inputs)
#define B    8
#define C    80
#define M    100
#define NPIX 16384          // 128*128
#define NT   128            // cells per block
#define NW   4              // waves per block (256 threads)

#define ALPHA_F 0.25f
#define EPS_F   1e-8f

// Bank swizzle for class rows: injective-ish map of c -> bank offset
#define SWZ(c) ((((c) & 31)) ^ ((((c) >> 5)) << 3))

// Order-preserving float -> uint32 map (total order; no NaNs expected here).
__device__ __forceinline__ uint32_t fkey(float f) {
    uint32_t u = __float_as_uint(f);
    return (u & 0x80000000u) ? ~u : (u | 0x80000000u);
}

// ---------------------------------------------------------------------------
// init: one wave per (b,m). cid = first argmax of one-hot row; keys = +inf.
// ---------------------------------------------------------------------------
__global__ __launch_bounds__(256) void init_kernel(
    const float* __restrict__ cls_true,   // (B*M, C)
    int* __restrict__ cids,
    unsigned long long* __restrict__ keys)
{
    const int bm   = blockIdx.x * NW + (threadIdx.x >> 6);
    const int lane = threadIdx.x & 63;
    if (bm >= B * M) return;

    const float* ct = cls_true + (size_t)bm * C;
    // key = (fkey(v) << 32) | (C-1-c): max over keys -> max v, tie -> min c
    const float v0 = ct[lane];
    unsigned long long k =
        ((unsigned long long)fkey(v0) << 32) | (unsigned int)(C - 1 - lane);
    if (lane + 64 < C) {
        const float v1 = ct[lane + 64];
        unsigned long long k1 =
            ((unsigned long long)fkey(v1) << 32) | (unsigned int)(C - 1 - (lane + 64));
        if (k1 > k) k = k1;
    }
    #pragma unroll
    for (int off = 32; off > 0; off >>= 1) {
        unsigned long long o = __shfl_xor(k, off, 64);
        if (o > k) k = o;
    }
    if (lane == 0) {
        cids[bm] = C - 1 - (int)(k & 0xFFFFFFFFull);
        keys[bm] = 0xFFFFFFFFFFFFFFFFull;
    }
}

// ---------------------------------------------------------------------------
// fused match, lane-owns-m: block = (128-cell tile, b). Stage focal costs D
// (bank-swizzled) + per-cell boxes in LDS. Lane l of wave w owns target
// m=(w&1)*64+l and serially min-scans 64 cells ((w>>1) selects the half) from
// registers; one packed-key atomicMin per lane. No shuffles, no barriers in
// the scan.
// ---------------------------------------------------------------------------
__global__ __launch_bounds__(256) void match_kernel(
    const float* __restrict__ cls_pred,   // (B, NPIX, C)
    const float* __restrict__ loc_pred,   // (B, NPIX, 4)
    const float* __restrict__ loc_true,   // (B, M, 4)
    const int*   __restrict__ cids,       // (B*M)
    unsigned long long* __restrict__ keys)// (B*M)
{
#pragma clang fp contract(off)
    __shared__ float  D[C * NT];          // 40,960 B, addr c*NT + (n ^ SWZ(c))
    __shared__ float4 bx4[NT];            //  2,048 B: scaled y1,x1,y2,x2
    __shared__ float  bpa[NT];            //    512 B: p_area

    const int b    = blockIdx.y;
    const int n0   = blockIdx.x * NT;
    const int tid  = threadIdx.x;
    const int lane = tid & 63;
    const int w    = tid >> 6;

    // ---- stage focal class-cost tile: float4 global loads, swizzled LDS ----
    const float4* src4 = (const float4*)(cls_pred + ((size_t)b * NPIX + n0) * C);
    #pragma unroll
    for (int it = 0; it < NT * C / 4 / 256; ++it) {   // 10 iters
        const int idx4 = it * 256 + tid;
        const int n    = idx4 / 20;                   // 80/4 = 20 float4 per cell
        const int c0   = (idx4 - n * 20) * 4;
        const float4 v = src4[idx4];
        const float pv[4] = { v.x, v.y, v.z, v.w };
        #pragma unroll
        for (int jj = 0; jj < 4; ++jj) {
            const int c = c0 + jj;
            const float p = pv[jj];
            const float q = 1.0f - p;
            const float pos = (ALPHA_F * (q * q)) * (-logf(p + EPS_F));
            const float neg = ((1.0f - ALPHA_F) * (p * p)) * (-logf(q + EPS_F));
            D[c * NT + (n ^ SWZ(c))] = pos - neg;
        }
    }

    // ---- per-cell scaled boxes (one thread per cell) ----
    if (tid < NT) {
        const float inv = 1.0f / 128.0f;
        const float4 lp = *(const float4*)(loc_pred + ((size_t)b * NPIX + n0 + tid) * 4);
        const float py1 = lp.x * inv;
        const float px1 = lp.y * inv;
        const float py2 = lp.z * inv;
        const float px2 = lp.w * inv;
        bx4[tid] = make_float4(py1, px1, py2, px2);
        bpa[tid] = fmaxf(py2 - py1, 0.0f) * fmaxf(px2 - px1, 0.0f);
    }

    __syncthreads();

    // ---- scan: lane owns m, serial over 64 cells of this wave's half ----
    const int mm = (w & 1) * 64 + lane;
    if (mm < M) {
        const int bm  = b * M + mm;
        const int cid = cids[bm];
        const float4 lt = *(const float4*)(loc_true + (size_t)bm * 4);
        const float ty1 = lt.x, tx1 = lt.y, ty2 = lt.z, tx2 = lt.w;
        const float t_area = fmaxf(ty2 - ty1, 0.0f) * fmaxf(tx2 - tx1, 0.0f);

        const int drow  = cid * NT;
        const int sw    = SWZ(cid);
        const int jbase = (w >> 1) * 64;

        float bestv = __builtin_huge_valf();
        int   bestn = 0;

        #pragma unroll 16
        for (int j = 0; j < 64; ++j) {
            const int cell = jbase + j;
            const float  d  = D[drow + (cell ^ sw)];   // per-lane gather
            const float4 bx = bx4[cell];               // uniform -> broadcast
            const float  pa = bpa[cell];
            const float py1 = bx.x, px1 = bx.y, py2 = bx.z, px2 = bx.w;

            // reg: sum(|loc_true - loc_p|), left-assoc like np
            const float r = ((fabsf(ty1 - py1) + fabsf(tx1 - px1))
                             + fabsf(ty2 - py2)) + fabsf(tx2 - px2);

            // giou
            const float ih = fmaxf(fminf(py2, ty2) - fmaxf(py1, ty1), 0.0f);
            const float iw = fmaxf(fminf(px2, tx2) - fmaxf(px1, tx1), 0.0f);
            const float inter = ih * iw;
            const float uni   = (pa + t_area) - inter;
            const float iou   = (uni > 0.0f) ? (inter / fmaxf(uni, EPS_F)) : 0.0f;
            const float eh = fmaxf(py2, ty2) - fminf(py1, ty1);
            const float ew = fmaxf(px2, tx2) - fminf(px1, tx1);
            const float enc = eh * ew;
            const float pen = (enc > 0.0f) ? ((enc - uni) / fmaxf(enc, EPS_F)) : 0.0f;
            const float gl  = 1.0f - (iou - pen);

            const float total = ((2.0f * d) + (5.0f * r)) + (2.0f * gl);

            if (total < bestv) { bestv = total; bestn = n0 + cell; }  // strict < => first index
        }

        const unsigned long long key =
            ((unsigned long long)fkey(bestv) << 32) | (unsigned int)bestn;
        atomicMin(&keys[bm], key);
    }
}

// ---------------------------------------------------------------------------
// writeout: unpack to (b, argmin, cid) int32
// ---------------------------------------------------------------------------
__global__ void write_out_kernel(const unsigned long long* __restrict__ keys,
                                 const int* __restrict__ cids,
                                 int* __restrict__ out) {
    int i = blockIdx.x * blockDim.x + threadIdx.x;
    if (i >= B * M) return;
    out[i * 3 + 0] = i / M;
    out[i * 3 + 1] = (int)(keys[i] & 0xFFFFFFFFull);
    out[i * 3 + 2] = cids[i];
}

// ===========================================================================
extern "C" void kernel_launch(void* const* d_in, const int* in_sizes, int n_in,
                              void* d_out, int out_size, void* d_ws, size_t ws_size,
                              hipStream_t stream) {
    const float* cls_pred = (const float*)d_in[0];
    const float* loc_pred = (const float*)d_in[1];
    const float* cls_true = (const float*)d_in[2];
    const float* loc_true = (const float*)d_in[3];
    int* out = (int*)d_out;

    unsigned long long* keys = (unsigned long long*)d_ws;
    int* cids = (int*)((char*)d_ws + (size_t)B * M * sizeof(unsigned long long));

    init_kernel<<<(B * M + NW - 1) / NW, 256, 0, stream>>>(cls_true, cids, keys);
    match_kernel<<<dim3(NPIX / NT, B), 256, 0, stream>>>(
        cls_pred, loc_pred, loc_true, cids, keys);
    write_out_kernel<<<(B * M + 255) / 256, 256, 0, stream>>>(keys, cids, out);
}

// Round 6
// 65.781 us; speedup vs baseline: 1.2389x; 1.0036x over previous
//
#include <hip/hip_runtime.h>
#include <stdint.h>

// Problem dims (fixed by the reference's setup_inputs)
#define B    8
#define C    80
#define M    100
#define NPIX 16384          // 128*128
#define NT   32             // cells per block
#define BT   128            // threads per block (2 waves)
#define NW   4              // waves per block in init kernel (256 threads)

#define ALPHA_F 0.25f
#define EPS_F   1e-8f

// Bank swizzle for class rows: spreads per-cid gathers across banks
#define SWZ(c) ((((c) & 31)) ^ ((((c) >> 5)) << 3))

// Order-preserving float -> uint32 map (total order; no NaNs expected here).
__device__ __forceinline__ uint32_t fkey(float f) {
    uint32_t u = __float_as_uint(f);
    return (u & 0x80000000u) ? ~u : (u | 0x80000000u);
}

// ---------------------------------------------------------------------------
// init: one wave per (b,m). cid = first argmax of one-hot row; keys = +inf.
// ---------------------------------------------------------------------------
__global__ __launch_bounds__(256) void init_kernel(
    const float* __restrict__ cls_true,   // (B*M, C)
    int* __restrict__ cids,
    unsigned long long* __restrict__ keys)
{
    const int bm   = blockIdx.x * NW + (threadIdx.x >> 6);
    const int lane = threadIdx.x & 63;
    if (bm >= B * M) return;

    const float* ct = cls_true + (size_t)bm * C;
    // key = (fkey(v) << 32) | (C-1-c): max over keys -> max v, tie -> min c
    const float v0 = ct[lane];
    unsigned long long k =
        ((unsigned long long)fkey(v0) << 32) | (unsigned int)(C - 1 - lane);
    if (lane + 64 < C) {
        const float v1 = ct[lane + 64];
        unsigned long long k1 =
            ((unsigned long long)fkey(v1) << 32) | (unsigned int)(C - 1 - (lane + 64));
        if (k1 > k) k = k1;
    }
    #pragma unroll
    for (int off = 32; off > 0; off >>= 1) {
        unsigned long long o = __shfl_xor(k, off, 64);
        if (o > k) k = o;
    }
    if (lane == 0) {
        cids[bm] = C - 1 - (int)(k & 0xFFFFFFFFull);
        keys[bm] = 0xFFFFFFFFFFFFFFFFull;
    }
}

// ---------------------------------------------------------------------------
// fused match, lane-owns-m, small tile for occupancy: block = (32-cell tile, b),
// 128 threads. Stage focal costs D (bank-swizzled) + per-cell boxes in LDS.
// Lane l of wave w owns target m = w*64 + l (m < 100) and serially min-scans
// all 32 cells; one packed-key atomicMin per lane. ~10.9 KB LDS -> 14 blocks/CU.
// ---------------------------------------------------------------------------
__global__ __launch_bounds__(BT, 6) void match_kernel(
    const float* __restrict__ cls_pred,   // (B, NPIX, C)
    const float* __restrict__ loc_pred,   // (B, NPIX, 4)
    const float* __restrict__ loc_true,   // (B, M, 4)
    const int*   __restrict__ cids,       // (B*M)
    unsigned long long* __restrict__ keys)// (B*M)
{
#pragma clang fp contract(off)
    __shared__ float  D[C * NT];          // 10,240 B, addr c*NT + ((n ^ SWZ(c)) & 31)
    __shared__ float4 bx4[NT];            //    512 B: scaled y1,x1,y2,x2
    __shared__ float  bpa[NT];            //    128 B: p_area

    const int b    = blockIdx.y;
    const int n0   = blockIdx.x * NT;
    const int tid  = threadIdx.x;
    const int lane = tid & 63;
    const int w    = tid >> 6;

    // ---- stage focal class-cost tile: float4 global loads, swizzled LDS ----
    const float4* src4 = (const float4*)(cls_pred + ((size_t)b * NPIX + n0) * C);
    #pragma unroll
    for (int it = 0; it < NT * C / 4 / BT; ++it) {   // 5 iters
        const int idx4 = it * BT + tid;
        const int n    = idx4 / 20;                   // 80/4 = 20 float4 per cell
        const int c0   = (idx4 - n * 20) * 4;
        const float4 v = src4[idx4];
        const float pv[4] = { v.x, v.y, v.z, v.w };
        #pragma unroll
        for (int jj = 0; jj < 4; ++jj) {
            const int c = c0 + jj;
            const float p = pv[jj];
            const float q = 1.0f - p;
            const float pos = (ALPHA_F * (q * q)) * (-logf(p + EPS_F));
            const float neg = ((1.0f - ALPHA_F) * (p * p)) * (-logf(q + EPS_F));
            D[c * NT + ((n ^ SWZ(c)) & (NT - 1))] = pos - neg;
        }
    }

    // ---- per-cell scaled boxes (one thread per cell) ----
    if (tid < NT) {
        const float inv = 1.0f / 128.0f;
        const float4 lp = *(const float4*)(loc_pred + ((size_t)b * NPIX + n0 + tid) * 4);
        const float py1 = lp.x * inv;
        const float px1 = lp.y * inv;
        const float py2 = lp.z * inv;
        const float px2 = lp.w * inv;
        bx4[tid] = make_float4(py1, px1, py2, px2);
        bpa[tid] = fmaxf(py2 - py1, 0.0f) * fmaxf(px2 - px1, 0.0f);
    }

    __syncthreads();

    // ---- scan: lane owns m, serial over all 32 cells ----
    const int mm = w * 64 + lane;
    if (mm < M) {
        const int bm  = b * M + mm;
        const int cid = cids[bm];
        const float4 lt = *(const float4*)(loc_true + (size_t)bm * 4);
        const float ty1 = lt.x, tx1 = lt.y, ty2 = lt.z, tx2 = lt.w;
        const float t_area = fmaxf(ty2 - ty1, 0.0f) * fmaxf(tx2 - tx1, 0.0f);

        const int drow = cid * NT;
        const int sw   = SWZ(cid) & (NT - 1);

        float bestv = __builtin_huge_valf();
        int   bestn = 0;

        #pragma unroll 8
        for (int j = 0; j < NT; ++j) {
            const float  d  = D[drow + (j ^ sw)];      // per-lane gather
            const float4 bx = bx4[j];                  // uniform -> broadcast
            const float  pa = bpa[j];
            const float py1 = bx.x, px1 = bx.y, py2 = bx.z, px2 = bx.w;

            // reg: sum(|loc_true - loc_p|), left-assoc like np
            const float r = ((fabsf(ty1 - py1) + fabsf(tx1 - px1))
                             + fabsf(ty2 - py2)) + fabsf(tx2 - px2);

            // giou
            const float ih = fmaxf(fminf(py2, ty2) - fmaxf(py1, ty1), 0.0f);
            const float iw = fmaxf(fminf(px2, tx2) - fmaxf(px1, tx1), 0.0f);
            const float inter = ih * iw;
            const float uni   = (pa + t_area) - inter;
            const float iou   = (uni > 0.0f) ? (inter / fmaxf(uni, EPS_F)) : 0.0f;
            const float eh = fmaxf(py2, ty2) - fminf(py1, ty1);
            const float ew = fmaxf(px2, tx2) - fminf(px1, tx1);
            const float enc = eh * ew;
            const float pen = (enc > 0.0f) ? ((enc - uni) / fmaxf(enc, EPS_F)) : 0.0f;
            const float gl  = 1.0f - (iou - pen);

            const float total = ((2.0f * d) + (5.0f * r)) + (2.0f * gl);

            if (total < bestv) { bestv = total; bestn = n0 + j; }  // strict < => first index
        }

        const unsigned long long key =
            ((unsigned long long)fkey(bestv) << 32) | (unsigned int)bestn;
        atomicMin(&keys[bm], key);
    }
}

// ---------------------------------------------------------------------------
// writeout: unpack to (b, argmin, cid) int32
// ---------------------------------------------------------------------------
__global__ void write_out_kernel(const unsigned long long* __restrict__ keys,
                                 const int* __restrict__ cids,
                                 int* __restrict__ out) {
    int i = blockIdx.x * blockDim.x + threadIdx.x;
    if (i >= B * M) return;
    out[i * 3 + 0] = i / M;
    out[i * 3 + 1] = (int)(keys[i] & 0xFFFFFFFFull);
    out[i * 3 + 2] = cids[i];
}

// ===========================================================================
extern "C" void kernel_launch(void* const* d_in, const int* in_sizes, int n_in,
                              void* d_out, int out_size, void* d_ws, size_t ws_size,
                              hipStream_t stream) {
    const float* cls_pred = (const float*)d_in[0];
    const float* loc_pred = (const float*)d_in[1];
    const float* cls_true = (const float*)d_in[2];
    const float* loc_true = (const float*)d_in[3];
    int* out = (int*)d_out;

    unsigned long long* keys = (unsigned long long*)d_ws;
    int* cids = (int*)((char*)d_ws + (size_t)B * M * sizeof(unsigned long long));

    init_kernel<<<(B * M + NW - 1) / NW, 256, 0, stream>>>(cls_true, cids, keys);
    match_kernel<<<dim3(NPIX / NT, B), BT, 0, stream>>>(
        cls_pred, loc_pred, loc_true, cids, keys);
    write_out_kernel<<<(B * M + 255) / 256, 256, 0, stream>>>(keys, cids, out);
}

// Round 7
// 60.332 us; speedup vs baseline: 1.3508x; 1.0903x over previous
//
#include <hip/hip_runtime.h>
#include <stdint.h>

// Problem dims (fixed by the reference's setup_inputs)
#define B    8
#define C    80
#define M    100
#define NPIX 16384          // 128*128
#define NT   32             // cells per LDS tile
#define KT   2              // tiles per block (double-buffered)
#define BT   128            // threads per block (2 waves)
#define NW   4              // waves per block in init kernel (256 threads)

#define ALPHA_F 0.25f
#define EPS_F   1e-8f

// Bank swizzle for class rows: spreads per-cid gathers across banks
#define SWZ(c) ((((c) & 31)) ^ ((((c) >> 5)) << 3))

// Order-preserving float -> uint32 map (total order; no NaNs expected here).
__device__ __forceinline__ uint32_t fkey(float f) {
    uint32_t u = __float_as_uint(f);
    return (u & 0x80000000u) ? ~u : (u | 0x80000000u);
}

// ---------------------------------------------------------------------------
// init: one wave per (b,m). cid = first argmax of one-hot row; keys = +inf.
// ---------------------------------------------------------------------------
__global__ __launch_bounds__(256) void init_kernel(
    const float* __restrict__ cls_true,   // (B*M, C)
    int* __restrict__ cids,
    unsigned long long* __restrict__ keys)
{
    const int bm   = blockIdx.x * NW + (threadIdx.x >> 6);
    const int lane = threadIdx.x & 63;
    if (bm >= B * M) return;

    const float* ct = cls_true + (size_t)bm * C;
    // key = (fkey(v) << 32) | (C-1-c): max over keys -> max v, tie -> min c
    const float v0 = ct[lane];
    unsigned long long k =
        ((unsigned long long)fkey(v0) << 32) | (unsigned int)(C - 1 - lane);
    if (lane + 64 < C) {
        const float v1 = ct[lane + 64];
        unsigned long long k1 =
            ((unsigned long long)fkey(v1) << 32) | (unsigned int)(C - 1 - (lane + 64));
        if (k1 > k) k = k1;
    }
    #pragma unroll
    for (int off = 32; off > 0; off >>= 1) {
        unsigned long long o = __shfl_xor(k, off, 64);
        if (o > k) k = o;
    }
    if (lane == 0) {
        cids[bm] = C - 1 - (int)(k & 0xFFFFFFFFull);
        keys[bm] = 0xFFFFFFFFFFFFFFFFull;
    }
}

// ---------------------------------------------------------------------------
// prep: pbox[b][n][8] = {py1,px1,py2,px2,p_area,0,0,0} (scaled), 32B/cell so
// the match kernel can read it with uniform (scalar) 32B-aligned loads.
// ---------------------------------------------------------------------------
__global__ __launch_bounds__(256) void prep_kernel(
    const float* __restrict__ loc_pred,   // (B, NPIX, 4)
    float* __restrict__ pbox)             // (B*NPIX, 8)
{
#pragma clang fp contract(off)
    const int i = blockIdx.x * 256 + threadIdx.x;
    if (i >= B * NPIX) return;
    const float inv = 1.0f / 128.0f;
    const float4 lp = ((const float4*)loc_pred)[i];
    const float py1 = lp.x * inv;
    const float px1 = lp.y * inv;
    const float py2 = lp.z * inv;
    const float px2 = lp.w * inv;
    const float pa  = fmaxf(py2 - py1, 0.0f) * fmaxf(px2 - px1, 0.0f);
    float4* dst = (float4*)pbox + (size_t)i * 2;
    dst[0] = make_float4(py1, px1, py2, px2);
    dst[1] = make_float4(pa, 0.0f, 0.0f, 0.0f);
}

// ---------------------------------------------------------------------------
// fused match: block = (2 x 32-cell tiles, b), 128 threads, lane-owns-m.
// D tiles double-buffered in LDS (bank-swizzled); boxes come from pbox via
// wave-uniform scalar loads; next tile's global loads issued before the scan.
// One packed-key atomicMin per lane per block.
// ---------------------------------------------------------------------------
__global__ __launch_bounds__(BT) void match_kernel(
    const float* __restrict__ cls_pred,   // (B, NPIX, C)
    const float* __restrict__ pbox,       // (B*NPIX, 8)
    const float* __restrict__ loc_true,   // (B, M, 4)
    const int*   __restrict__ cids,       // (B*M)
    unsigned long long* __restrict__ keys)// (B*M)
{
#pragma clang fp contract(off)
    __shared__ float D[2][C * NT];        // 2 x 10,240 B

    const int b      = blockIdx.y;
    const int base_n = blockIdx.x * (NT * KT);
    const int tid    = threadIdx.x;
    const int lane   = tid & 63;
    const int w      = tid >> 6;

    // ---- per-lane target (m) data ----
    const int  mm  = w * 64 + lane;
    const bool act = (mm < M);
    const int  bm  = b * M + (act ? mm : 0);
    int cid = 0, drow = 0, sw = 0;
    float ty1 = 0.f, tx1 = 0.f, ty2 = 0.f, tx2 = 0.f, t_area = 0.f;
    if (act) {
        cid = cids[bm];
        const float4 lt = *(const float4*)(loc_true + (size_t)bm * 4);
        ty1 = lt.x; tx1 = lt.y; ty2 = lt.z; tx2 = lt.w;
        t_area = fmaxf(ty2 - ty1, 0.0f) * fmaxf(tx2 - tx1, 0.0f);
        drow = cid * NT;
        sw   = SWZ(cid) & (NT - 1);
    }

    // ---- stage tile 0 into D[0] ----
    {
        const float4* src4 = (const float4*)(cls_pred + ((size_t)b * NPIX + base_n) * C);
        #pragma unroll
        for (int it = 0; it < NT * C / 4 / BT; ++it) {   // 5 iters
            const int idx4 = it * BT + tid;
            const int n    = idx4 / 20;
            const int c0   = (idx4 - n * 20) * 4;
            const float4 v = src4[idx4];
            const float pv[4] = { v.x, v.y, v.z, v.w };
            #pragma unroll
            for (int jj = 0; jj < 4; ++jj) {
                const int c = c0 + jj;
                const float p = pv[jj];
                const float q = 1.0f - p;
                const float pos = (ALPHA_F * (q * q)) * (-logf(p + EPS_F));
                const float neg = ((1.0f - ALPHA_F) * (p * p)) * (-logf(q + EPS_F));
                D[0][c * NT + ((n ^ SWZ(c)) & (NT - 1))] = pos - neg;
            }
        }
    }
    __syncthreads();

    float bestv = __builtin_huge_valf();
    int   bestn = 0;

    #pragma unroll
    for (int t = 0; t < KT; ++t) {
        const int cur = t & 1;
        const int tn0 = base_n + t * NT;

        // ---- issue next tile's global loads (hide latency under the scan) ----
        float4 ld[5];
        if (t + 1 < KT) {
            const float4* src4 =
                (const float4*)(cls_pred + ((size_t)b * NPIX + tn0 + NT) * C);
            #pragma unroll
            for (int it = 0; it < 5; ++it) ld[it] = src4[it * BT + tid];
        }

        // ---- scan tile t: boxes via uniform scalar loads, D via LDS gather ----
        if (act) {
            const float* pb = pbox + ((size_t)(b * NPIX) + tn0) * 8;
            #pragma unroll 8
            for (int j = 0; j < NT; ++j) {
                const float d   = D[cur][drow + (j ^ sw)];   // per-lane gather
                const float py1 = pb[j * 8 + 0];             // uniform -> SGPR
                const float px1 = pb[j * 8 + 1];
                const float py2 = pb[j * 8 + 2];
                const float px2 = pb[j * 8 + 3];
                const float pa  = pb[j * 8 + 4];

                // reg: sum(|loc_true - loc_p|), left-assoc like np
                const float r = ((fabsf(ty1 - py1) + fabsf(tx1 - px1))
                                 + fabsf(ty2 - py2)) + fabsf(tx2 - px2);

                // giou
                const float ih = fmaxf(fminf(py2, ty2) - fmaxf(py1, ty1), 0.0f);
                const float iw = fmaxf(fminf(px2, tx2) - fmaxf(px1, tx1), 0.0f);
                const float inter = ih * iw;
                const float uni   = (pa + t_area) - inter;
                const float iou   = (uni > 0.0f) ? (inter / fmaxf(uni, EPS_F)) : 0.0f;
                const float eh = fmaxf(py2, ty2) - fminf(py1, ty1);
                const float ew = fmaxf(px2, tx2) - fminf(px1, tx1);
                const float enc = eh * ew;
                const float pen = (enc > 0.0f) ? ((enc - uni) / fmaxf(enc, EPS_F)) : 0.0f;
                const float gl  = 1.0f - (iou - pen);

                const float total = ((2.0f * d) + (5.0f * r)) + (2.0f * gl);

                if (total < bestv) { bestv = total; bestn = tn0 + j; }  // strict < => first index
            }
        }

        // ---- focal compute for next tile into the other buffer ----
        if (t + 1 < KT) {
            #pragma unroll
            for (int it = 0; it < 5; ++it) {
                const int idx4 = it * BT + tid;
                const int n    = idx4 / 20;
                const int c0   = (idx4 - n * 20) * 4;
                const float pv[4] = { ld[it].x, ld[it].y, ld[it].z, ld[it].w };
                #pragma unroll
                for (int jj = 0; jj < 4; ++jj) {
                    const int c = c0 + jj;
                    const float p = pv[jj];
                    const float q = 1.0f - p;
                    const float pos = (ALPHA_F * (q * q)) * (-logf(p + EPS_F));
                    const float neg = ((1.0f - ALPHA_F) * (p * p)) * (-logf(q + EPS_F));
                    D[1 - cur][c * NT + ((n ^ SWZ(c)) & (NT - 1))] = pos - neg;
                }
            }
            __syncthreads();
        }
    }

    if (act) {
        const unsigned long long key =
            ((unsigned long long)fkey(bestv) << 32) | (unsigned int)bestn;
        atomicMin(&keys[bm], key);
    }
}

// ---------------------------------------------------------------------------
// writeout: unpack to (b, argmin, cid) int32
// ---------------------------------------------------------------------------
__global__ void write_out_kernel(const unsigned long long* __restrict__ keys,
                                 const int* __restrict__ cids,
                                 int* __restrict__ out) {
    int i = blockIdx.x * blockDim.x + threadIdx.x;
    if (i >= B * M) return;
    out[i * 3 + 0] = i / M;
    out[i * 3 + 1] = (int)(keys[i] & 0xFFFFFFFFull);
    out[i * 3 + 2] = cids[i];
}

// ===========================================================================
extern "C" void kernel_launch(void* const* d_in, const int* in_sizes, int n_in,
                              void* d_out, int out_size, void* d_ws, size_t ws_size,
                              hipStream_t stream) {
    const float* cls_pred = (const float*)d_in[0];
    const float* loc_pred = (const float*)d_in[1];
    const float* cls_true = (const float*)d_in[2];
    const float* loc_true = (const float*)d_in[3];
    int* out = (int*)d_out;

    // ws layout: keys (6400 B) | cids (3200 B) | pad | pbox (4 MB, 32B-aligned)
    unsigned long long* keys = (unsigned long long*)d_ws;
    int*   cids = (int*)((char*)d_ws + (size_t)B * M * sizeof(unsigned long long));
    float* pbox = (float*)((char*)d_ws + 16384);

    init_kernel<<<(B * M + NW - 1) / NW, 256, 0, stream>>>(cls_true, cids, keys);
    prep_kernel<<<(B * NPIX + 255) / 256, 256, 0, stream>>>(loc_pred, pbox);
    match_kernel<<<dim3(NPIX / (NT * KT), B), BT, 0, stream>>>(
        cls_pred, pbox, loc_true, cids, keys);
    write_out_kernel<<<(B * M + 255) / 256, 256, 0, stream>>>(keys, cids, out);
}